// Round 7
// baseline (488.755 us; speedup 1.0000x reference)
//
#include <hip/hip_runtime.h>

#define NNODES 50000
#define NEDGES 800000
#define NGRAPH 512

typedef short bf16x8 __attribute__((ext_vector_type(8)));
typedef unsigned short u16x8 __attribute__((ext_vector_type(8)));
typedef float f32x4 __attribute__((ext_vector_type(4)));

// ---------- bf16 <-> fp32 helpers ----------
static __device__ __forceinline__ float b2f(unsigned short u) {
    return __uint_as_float(((unsigned)u) << 16);
}
static __device__ __forceinline__ unsigned short f2b(float f) {
    unsigned u = __float_as_uint(f);
    unsigned r = (u + 0x7fffu + ((u >> 16) & 1u)) >> 16;  // round-nearest-even
    return (unsigned short)r;
}

// row-fragment loads (bf16 rows)
static __device__ __forceinline__ void ldrow(const unsigned short* X, size_t off, float (&v)[2]) {
    unsigned u = *(const unsigned*)(X + off);
    v[0] = b2f((unsigned short)(u & 0xffff));
    v[1] = b2f((unsigned short)(u >> 16));
}
static __device__ __forceinline__ void ldrow(const unsigned short* X, size_t off, float (&v)[4]) {
    uint2 u = *(const uint2*)(X + off);
    v[0] = b2f((unsigned short)(u.x & 0xffff));
    v[1] = b2f((unsigned short)(u.x >> 16));
    v[2] = b2f((unsigned short)(u.y & 0xffff));
    v[3] = b2f((unsigned short)(u.y >> 16));
}

// ---------- setup: deg_cnt init + gp zero ----------
__global__ void k_setup(unsigned long long* deg_cnt, int* gp) {
    int i = blockIdx.x * 256 + threadIdx.x;
    if (i < NNODES) deg_cnt[i] = (unsigned long long)(1u << 24);  // self-loop w=1 (8.24 fixed)
    if (i < NGRAPH * 512) gp[i] = 0;                              // +0.0f bits
}

// packed u64 atomic: hi32 = count, lo32 = 8.24 fixed-point weighted degree
__global__ void k_count(const int* __restrict__ ei, const float* __restrict__ ew,
                        unsigned long long* deg_cnt) {
    int e = blockIdx.x * 256 + threadIdx.x;
    if (e < NEDGES) {
        int d = ei[NEDGES + e];
        unsigned fixed = __float2uint_rn(ew[e] * 16777216.0f);  // 2^24; ew in [0,1)
        atomicAdd(&deg_cnt[d], ((unsigned long long)1 << 32) | fixed);
    }
}

// ---------- 3-phase exclusive scan (+dinv unpack fused into phase 1) ----------
__global__ void k_scan1(const unsigned long long* __restrict__ deg_cnt,
                        float* __restrict__ dinv,
                        int* __restrict__ ofs, int* __restrict__ bsum, int n) {
    __shared__ int wsum[4];
    const int tid = threadIdx.x, lane = tid & 63, wid = tid >> 6;
    const int idx = blockIdx.x * 256 + tid;
    int v = 0;
    if (idx < n) {
        unsigned long long dc = deg_cnt[idx];
        v = (int)(dc >> 32);
        dinv[idx] = rsqrtf((float)(unsigned)(dc & 0xffffffffull) * 5.9604645e-8f);  // *2^-24
    }
    int s = v;
    #pragma unroll
    for (int off = 1; off < 64; off <<= 1) {
        int y = __shfl_up(s, off, 64);
        if (lane >= off) s += y;
    }
    if (lane == 63) wsum[wid] = s;
    __syncthreads();
    int waveoff = 0;
    for (int w = 0; w < wid; ++w) waveoff += wsum[w];
    if (idx < n) ofs[idx] = waveoff + s - v;
    if (tid == 255) bsum[blockIdx.x] = waveoff + s;
}
__global__ void k_scan2(int* __restrict__ bsum, int nb) {
    __shared__ int wsum[4];
    const int tid = threadIdx.x, lane = tid & 63, wid = tid >> 6;
    int v = (tid < nb) ? bsum[tid] : 0;
    int s = v;
    #pragma unroll
    for (int off = 1; off < 64; off <<= 1) {
        int y = __shfl_up(s, off, 64);
        if (lane >= off) s += y;
    }
    if (lane == 63) wsum[wid] = s;
    __syncthreads();
    int waveoff = 0;
    for (int w = 0; w < wid; ++w) waveoff += wsum[w];
    if (tid < nb) bsum[tid] = waveoff + s - v;
    if (tid == 255) bsum[nb] = waveoff + s;
}
// final offsets into BOTH rowofs (read-only CSR) and cursor (atomic fill state)
__global__ void k_scan3(int* __restrict__ ofs, int* __restrict__ cursor,
                        const int* __restrict__ bsum, int n) {
    const int idx = blockIdx.x * 256 + threadIdx.x;
    if (idx < n) {
        int v = ofs[idx] + bsum[blockIdx.x];
        ofs[idx] = v;
        cursor[idx] = v;
    }
    if (idx == 0) ofs[n] = bsum[gridDim.x];
}

// per edge: one atomic + one packed 8B store. coef = ew*dinv[src] (dinv[dst] hoisted to aggregate)
__global__ void k_fill(const int* __restrict__ ei, const float* __restrict__ ew,
                       const float* __restrict__ dinv, int* cursor,
                       unsigned long long* __restrict__ edges) {
    int e = blockIdx.x * 256 + threadIdx.x;
    if (e < NEDGES) {
        int s = ei[e];
        int d = ei[NEDGES + e];
        float c = ew[e] * dinv[s];
        int pos = atomicAdd(&cursor[d], 1);
        edges[pos] = ((unsigned long long)__float_as_uint(c) << 32) | (unsigned)s;
    }
}

// ---------- all 5 weight transposes in one kernel: W[K][N] fp32 -> WT[N][K] bf16 ----------
__global__ void k_wt_all(const float* __restrict__ W1, const float* __restrict__ W2,
                         const float* __restrict__ W3, const float* __restrict__ Wf1,
                         const float* __restrict__ Wf2,
                         unsigned short* __restrict__ T1, unsigned short* __restrict__ T2,
                         unsigned short* __restrict__ T3, unsigned short* __restrict__ Tf1,
                         unsigned short* __restrict__ Tf2) {
    int i = blockIdx.x * 256 + threadIdx.x;
    const float* W; unsigned short* T; int K, ns;
    if (i < 16384)        { W = W1;  T = T1;  K = 128;  ns = 7;  }
    else if (i < 49152)   { W = W2;  T = T2;  K = 128;  ns = 8;  i -= 16384; }
    else if (i < 180224)  { W = W3;  T = T3;  K = 256;  ns = 9;  i -= 49152; }
    else if (i < 704512)  { W = Wf1; T = Tf1; K = 512;  ns = 10; i -= 180224; }
    else if (i < 835584)  { W = Wf2; T = Tf2; K = 1024; ns = 7;  i -= 704512; }
    else return;
    int k = i >> ns, n = i & ((1 << ns) - 1);
    T[(size_t)n * K + k] = f2b(W[i]);
}

// fp32 -> bf16 elementwise (n4 = n/4)
__global__ void k_cvt4(const float* __restrict__ X, unsigned short* __restrict__ Y, int n4) {
    int i = blockIdx.x * 256 + threadIdx.x;
    if (i < n4) {
        float4 v = ((const float4*)X)[i];
        uint2 o;
        o.x = (unsigned)f2b(v.x) | ((unsigned)f2b(v.y) << 16);
        o.y = (unsigned)f2b(v.z) | ((unsigned)f2b(v.w) << 16);
        ((uint2*)Y)[i] = o;
    }
}

// ---------- aggregation: Z[i,:] = dinv[i] * (dinv[i]*X[i,:] + sum_e coef_e * X[col_e,:]) ----------
// wave-per-node, lane owns VEC elems (F = 64*VEC), packed (col,coef) edges, unroll x4.
template <int VEC>
__global__ __launch_bounds__(256) void k_aggregate(const unsigned short* __restrict__ X,
                                                   const int* __restrict__ row_ofs,
                                                   const unsigned long long* __restrict__ edges,
                                                   const float* __restrict__ dinv,
                                                   unsigned short* __restrict__ Z) {
    const int F = 64 * VEC;
    const int wave = threadIdx.x >> 6, lane = threadIdx.x & 63;
    const int node = blockIdx.x * 4 + wave;
    if (node >= NNODES) return;
    const int fo = lane * VEC;
    const float di = dinv[node];

    float acc[VEC], v[VEC];
    ldrow(X, (size_t)node * F + fo, v);
    #pragma unroll
    for (int j = 0; j < VEC; ++j) acc[j] = di * v[j];

    int e = row_ofs[node];
    const int end = row_ofs[node + 1];
    for (; e + 4 <= end; e += 4) {
        unsigned long long p0 = edges[e], p1 = edges[e + 1], p2 = edges[e + 2], p3 = edges[e + 3];
        float v0[VEC], v1[VEC], v2[VEC], v3[VEC];
        ldrow(X, (size_t)(unsigned)p0 * F + fo, v0);
        ldrow(X, (size_t)(unsigned)p1 * F + fo, v1);
        ldrow(X, (size_t)(unsigned)p2 * F + fo, v2);
        ldrow(X, (size_t)(unsigned)p3 * F + fo, v3);
        float c0 = __uint_as_float((unsigned)(p0 >> 32));
        float c1 = __uint_as_float((unsigned)(p1 >> 32));
        float c2 = __uint_as_float((unsigned)(p2 >> 32));
        float c3 = __uint_as_float((unsigned)(p3 >> 32));
        #pragma unroll
        for (int j = 0; j < VEC; ++j)
            acc[j] += c0 * v0[j] + c1 * v1[j] + c2 * v2[j] + c3 * v3[j];
    }
    for (; e < end; ++e) {
        unsigned long long pe = edges[e];
        float c = __uint_as_float((unsigned)(pe >> 32));
        ldrow(X, (size_t)(unsigned)pe * F + fo, v);
        #pragma unroll
        for (int j = 0; j < VEC; ++j) acc[j] += c * v[j];
    }

    if constexpr (VEC == 2) {
        unsigned o = (unsigned)f2b(di * acc[0]) | ((unsigned)f2b(di * acc[1]) << 16);
        *(unsigned*)(Z + (size_t)node * F + fo) = o;
    } else {
        uint2 o;
        o.x = (unsigned)f2b(di * acc[0]) | ((unsigned)f2b(di * acc[1]) << 16);
        o.y = (unsigned)f2b(di * acc[2]) | ((unsigned)f2b(di * acc[3]) << 16);
        *(uint2*)(Z + (size_t)node * F + fo) = o;
    }
}

// ---------- fused layer-1: aggregate(x16) -> As(LDS) -> MFMA @W1 -> relu -> h1 ----------
// N=128 (single n-block), K=128 fully LDS-resident. block = 64 rows, 4 waves.
__global__ __launch_bounds__(256) void k_l1_fused(const unsigned short* __restrict__ X,
                                                  const int* __restrict__ row_ofs,
                                                  const unsigned long long* __restrict__ edges,
                                                  const float* __restrict__ dinv,
                                                  const unsigned short* __restrict__ WT,
                                                  const float* __restrict__ bias,
                                                  unsigned short* __restrict__ C) {
    constexpr int LDK = 136;  // 128 + 8 shorts padding
    __shared__ unsigned short As[64 * LDK];
    __shared__ unsigned short Bs[128 * LDK];
    const int tid = threadIdx.x;
    const int m0 = blockIdx.x * 64;
    const int wave = tid >> 6, lane = tid & 63;

    // stage all of WT [128][128] into Bs
    #pragma unroll
    for (int cch = 0; cch < 8; ++cch) {
        int cid = cch * 256 + tid;
        int n = cid >> 4, kc = (cid & 15) * 8;
        *(u16x8*)&Bs[n * LDK + kc] = *(const u16x8*)(WT + n * 128 + kc);
    }

    // aggregate 16 rows per wave into As
    const int fo = lane * 2;
    for (int r = 0; r < 16; ++r) {
        const int row = wave * 16 + r;
        const int node = m0 + row;
        float a0 = 0.f, a1 = 0.f;
        if (node < NNODES) {
            const float di = dinv[node];
            float acc[2], v[2];
            ldrow(X, (size_t)node * 128 + fo, v);
            acc[0] = di * v[0]; acc[1] = di * v[1];
            int e = row_ofs[node];
            const int end = row_ofs[node + 1];
            for (; e + 4 <= end; e += 4) {
                unsigned long long p0 = edges[e], p1 = edges[e + 1], p2 = edges[e + 2], p3 = edges[e + 3];
                float v0[2], v1[2], v2[2], v3[2];
                ldrow(X, (size_t)(unsigned)p0 * 128 + fo, v0);
                ldrow(X, (size_t)(unsigned)p1 * 128 + fo, v1);
                ldrow(X, (size_t)(unsigned)p2 * 128 + fo, v2);
                ldrow(X, (size_t)(unsigned)p3 * 128 + fo, v3);
                float c0 = __uint_as_float((unsigned)(p0 >> 32));
                float c1 = __uint_as_float((unsigned)(p1 >> 32));
                float c2 = __uint_as_float((unsigned)(p2 >> 32));
                float c3 = __uint_as_float((unsigned)(p3 >> 32));
                acc[0] += c0 * v0[0] + c1 * v1[0] + c2 * v2[0] + c3 * v3[0];
                acc[1] += c0 * v0[1] + c1 * v1[1] + c2 * v2[1] + c3 * v3[1];
            }
            for (; e < end; ++e) {
                unsigned long long pe = edges[e];
                float c = __uint_as_float((unsigned)(pe >> 32));
                float v[2];
                ldrow(X, (size_t)(unsigned)pe * 128 + fo, v);
                acc[0] += c * v[0]; acc[1] += c * v[1];
            }
            a0 = di * acc[0]; a1 = di * acc[1];
        }
        *(unsigned*)&As[row * LDK + fo] = (unsigned)f2b(a0) | ((unsigned)f2b(a1) << 16);
    }
    __syncthreads();

    // MFMA: 2x2 wave grid, each wave 2(m) x 4(n) 16x16 tiles, K=128
    const int wm = (wave >> 1) * 32;
    const int wn = (wave & 1) * 64;
    const int quad = lane >> 4, mrow = lane & 15;
    f32x4 acc[2][4] = {};
    #pragma unroll
    for (int k0 = 0; k0 < 128; k0 += 32) {
        bf16x8 af[2], bf[4];
        #pragma unroll
        for (int mt = 0; mt < 2; ++mt)
            af[mt] = *(const bf16x8*)&As[(wm + mt * 16 + mrow) * LDK + k0 + quad * 8];
        #pragma unroll
        for (int nt = 0; nt < 4; ++nt)
            bf[nt] = *(const bf16x8*)&Bs[(wn + nt * 16 + mrow) * LDK + k0 + quad * 8];
        #pragma unroll
        for (int mt = 0; mt < 2; ++mt)
            #pragma unroll
            for (int nt = 0; nt < 4; ++nt)
                acc[mt][nt] = __builtin_amdgcn_mfma_f32_16x16x32_bf16(af[mt], bf[nt], acc[mt][nt], 0, 0, 0);
    }

    float bn[4];
    #pragma unroll
    for (int nt = 0; nt < 4; ++nt) bn[nt] = bias[wn + nt * 16 + mrow];
    #pragma unroll
    for (int mt = 0; mt < 2; ++mt) {
        #pragma unroll
        for (int r = 0; r < 4; ++r) {
            int row = m0 + wm + mt * 16 + quad * 4 + r;
            if (row < NNODES) {
                #pragma unroll
                for (int nt = 0; nt < 4; ++nt) {
                    float v = fmaxf(acc[mt][nt][r] + bn[nt], 0.f);
                    C[(size_t)row * 128 + wn + nt * 16 + mrow] = f2b(v);
                }
            }
        }
    }
}

// ---------- bf16 MFMA GEMM: C = epi(A[MxK] @ WT[NxK]^T + bias) ----------
// block 64(M) x 128(N), 4 waves (2x2 of 32x64), BK=32, 16x16x32 MFMA.
// CMODE 0: bf16 store + relu. 1: fp32 store, no relu. 2: fused per-graph relu+max-pool into gp.
// AFP: A is fp32 (converted to bf16 during staging).
template <int CMODE, int AFP>
__global__ __launch_bounds__(256) void k_gemm_mfma(const void* __restrict__ Av,
                                                   const unsigned short* __restrict__ WT,
                                                   const float* __restrict__ bias,
                                                   void* __restrict__ Cv,
                                                   const int* __restrict__ batch,
                                                   int* __restrict__ gp,
                                                   int M, int N, int K) {
    constexpr int LDK = 40;
    __shared__ unsigned short As[64 * LDK];
    __shared__ unsigned short Bs[128 * LDK];
    const int tid = threadIdx.x;
    const int m0 = blockIdx.y * 64, n0 = blockIdx.x * 128;
    const int wave = tid >> 6, lane = tid & 63;
    const int wm = (wave >> 1) * 32;
    const int wn = (wave & 1) * 64;
    const int quad = lane >> 4, mrow = lane & 15;

    const int ar = tid >> 2;
    const int ak = (tid & 3) * 8;
    const bool arow_ok = (m0 + ar) < M;
    const size_t aoff = (size_t)(m0 + ar) * K + ak;
    const unsigned short* Bg0 = WT + (size_t)(n0 + ar) * K + ak;
    const unsigned short* Bg1 = WT + (size_t)(n0 + ar + 64) * K + ak;

    f32x4 acc[2][4] = {};

    for (int k0 = 0; k0 < K; k0 += 32) {
        u16x8 av = {};
        if (arow_ok) {
            if constexpr (AFP) {
                const float* Af = (const float*)Av + aoff + k0;
                float4 f0 = *(const float4*)Af;
                float4 f1 = *(const float4*)(Af + 4);
                av[0] = (short)f2b(f0.x); av[1] = (short)f2b(f0.y);
                av[2] = (short)f2b(f0.z); av[3] = (short)f2b(f0.w);
                av[4] = (short)f2b(f1.x); av[5] = (short)f2b(f1.y);
                av[6] = (short)f2b(f1.z); av[7] = (short)f2b(f1.w);
            } else {
                av = *(const u16x8*)((const unsigned short*)Av + aoff + k0);
            }
        }
        u16x8 bv0 = *(const u16x8*)(Bg0 + k0);
        u16x8 bv1 = *(const u16x8*)(Bg1 + k0);
        *(u16x8*)&As[ar * LDK + ak] = av;
        *(u16x8*)&Bs[ar * LDK + ak] = bv0;
        *(u16x8*)&Bs[(ar + 64) * LDK + ak] = bv1;
        __syncthreads();
        bf16x8 af[2], bf[4];
        #pragma unroll
        for (int mt = 0; mt < 2; ++mt)
            af[mt] = *(const bf16x8*)&As[(wm + mt * 16 + mrow) * LDK + quad * 8];
        #pragma unroll
        for (int nt = 0; nt < 4; ++nt)
            bf[nt] = *(const bf16x8*)&Bs[(wn + nt * 16 + mrow) * LDK + quad * 8];
        #pragma unroll
        for (int mt = 0; mt < 2; ++mt)
            #pragma unroll
            for (int nt = 0; nt < 4; ++nt)
                acc[mt][nt] = __builtin_amdgcn_mfma_f32_16x16x32_bf16(af[mt], bf[nt], acc[mt][nt], 0, 0, 0);
        __syncthreads();
    }

    float bn[4];
    #pragma unroll
    for (int nt = 0; nt < 4; ++nt) bn[nt] = bias[n0 + wn + nt * 16 + mrow];

    if constexpr (CMODE == 0) {
        unsigned short* C = (unsigned short*)Cv;
        #pragma unroll
        for (int mt = 0; mt < 2; ++mt) {
            #pragma unroll
            for (int r = 0; r < 4; ++r) {
                int row = m0 + wm + mt * 16 + quad * 4 + r;
                if (row < M) {
                    #pragma unroll
                    for (int nt = 0; nt < 4; ++nt) {
                        float v = fmaxf(acc[mt][nt][r] + bn[nt], 0.f);
                        C[(size_t)row * N + n0 + wn + nt * 16 + mrow] = f2b(v);
                    }
                }
            }
        }
    } else if constexpr (CMODE == 1) {
        float* C = (float*)Cv;
        #pragma unroll
        for (int mt = 0; mt < 2; ++mt) {
            #pragma unroll
            for (int r = 0; r < 4; ++r) {
                int row = m0 + wm + mt * 16 + quad * 4 + r;
                if (row < M) {
                    #pragma unroll
                    for (int nt = 0; nt < 4; ++nt)
                        C[(size_t)row * N + n0 + wn + nt * 16 + mrow] = acc[mt][nt][r] + bn[nt];
                }
            }
        }
    } else {
        // fused pool: block's 64 rows span <=2 graphs (min graph size 97)
        __shared__ float pools[2][2][128];
        const int g0 = batch[m0];
        int last = m0 + 63; if (last >= M) last = M - 1;
        const int gl = batch[last];
        int  gid[8];
        bool rok[8];
        #pragma unroll
        for (int mt = 0; mt < 2; ++mt)
            #pragma unroll
            for (int r = 0; r < 4; ++r) {
                int row = m0 + wm + mt * 16 + quad * 4 + r;
                rok[mt * 4 + r] = row < M;
                gid[mt * 4 + r] = (row < M) ? batch[row] : -1;
            }
        #pragma unroll
        for (int nt = 0; nt < 4; ++nt) {
            float v0 = 0.f, v1 = 0.f;
            #pragma unroll
            for (int mt = 0; mt < 2; ++mt)
                #pragma unroll
                for (int r = 0; r < 4; ++r) {
                    if (rok[mt * 4 + r]) {
                        float v = fmaxf(acc[mt][nt][r] + bn[nt], 0.f);
                        if (gid[mt * 4 + r] == g0) v0 = fmaxf(v0, v);
                        else v1 = fmaxf(v1, v);
                    }
                }
            v0 = fmaxf(v0, __shfl_xor(v0, 16, 64));
            v0 = fmaxf(v0, __shfl_xor(v0, 32, 64));
            v1 = fmaxf(v1, __shfl_xor(v1, 16, 64));
            v1 = fmaxf(v1, __shfl_xor(v1, 32, 64));
            if (quad == 0) {
                int c = wn + nt * 16 + mrow;
                pools[wm >> 5][0][c] = v0;
                pools[wm >> 5][1][c] = v1;
            }
        }
        __syncthreads();
        int c = tid & 127, gi = tid >> 7;
        float v = fmaxf(pools[0][gi][c], pools[1][gi][c]);
        int g = gi ? gl : g0;
        if (gi == 0 || gl != g0)
            atomicMax(&gp[(size_t)g * N + n0 + c], __float_as_int(v));
    }
}

extern "C" void kernel_launch(void* const* d_in, const int* in_sizes, int n_in,
                              void* d_out, int out_size, void* d_ws, size_t ws_size,
                              hipStream_t stream) {
    const float* x   = (const float*)d_in[0];
    const float* ew  = (const float*)d_in[1];
    const float* W1  = (const float*)d_in[2];
    const float* b1  = (const float*)d_in[3];
    const float* W2  = (const float*)d_in[4];
    const float* b2  = (const float*)d_in[5];
    const float* W3  = (const float*)d_in[6];
    const float* b3  = (const float*)d_in[7];
    const float* Wf1 = (const float*)d_in[8];
    const float* bf1 = (const float*)d_in[9];
    const float* Wf2 = (const float*)d_in[10];
    const float* bf2 = (const float*)d_in[11];
    const int* ei    = (const int*)d_in[12];
    const int* batch = (const int*)d_in[13];
    float* out = (float*)d_out;
    (void)in_sizes; (void)n_in; (void)out_size; (void)ws_size;

    char* p = (char*)d_ws;
    auto alloc = [&](size_t bytes) -> char* {
        char* r = p;
        p += (bytes + 255) & ~(size_t)255;
        return r;
    };
    const int nbN = (NNODES + 255) / 256;   // 196
    unsigned long long* deg_cnt = (unsigned long long*)alloc((size_t)NNODES * 8);
    float* dinv   = (float*)alloc((size_t)NNODES * 4);
    int*   cursor = (int*)  alloc((size_t)NNODES * 4);
    int*   rowofs = (int*)  alloc((size_t)(NNODES + 1) * 4);
    int*   bsum   = (int*)  alloc((size_t)(nbN + 1) * 4);
    unsigned long long* edges = (unsigned long long*)alloc((size_t)NEDGES * 8);  // packed (coef,col)
    int*   gp     = (int*)  alloc((size_t)NGRAPH * 512 * 4);
    unsigned short* f1   = (unsigned short*)alloc((size_t)NGRAPH * 1024 * 2);
    unsigned short* wt1  = (unsigned short*)alloc((size_t)128 * 128 * 2);
    unsigned short* wt2  = (unsigned short*)alloc((size_t)256 * 128 * 2);
    unsigned short* wt3  = (unsigned short*)alloc((size_t)512 * 256 * 2);
    unsigned short* wtf1 = (unsigned short*)alloc((size_t)1024 * 512 * 2);
    unsigned short* wtf2 = (unsigned short*)alloc((size_t)128 * 1024 * 2);
    unsigned short* bufA = (unsigned short*)alloc((size_t)NNODES * 256 * 2);
    unsigned short* bufB = (unsigned short*)alloc((size_t)NNODES * 256 * 2);
    unsigned short* x16  = bufA;  // x16 (12.8MB) lives in bufA; dead after fused L1
    // total ~63 MB

    const int nbE = (NEDGES + 255) / 256;
    const int MB = (NNODES + 63) / 64;      // 782
    const int AGG = (NNODES + 3) / 4;

    // graph preprocessing (shared by all 3 conv layers)
    k_setup<<<1024, 256, 0, stream>>>(deg_cnt, gp);
    k_count<<<nbE, 256, 0, stream>>>(ei, ew, deg_cnt);
    k_scan1<<<nbN, 256, 0, stream>>>(deg_cnt, dinv, rowofs, bsum, NNODES);
    k_scan2<<<1, 256, 0, stream>>>(bsum, nbN);
    k_scan3<<<nbN, 256, 0, stream>>>(rowofs, cursor, bsum, NNODES);
    k_fill<<<nbE, 256, 0, stream>>>(ei, ew, dinv, cursor, edges);
    k_wt_all<<<(835584 + 255) / 256, 256, 0, stream>>>(W1, W2, W3, Wf1, Wf2,
                                                       wt1, wt2, wt3, wtf1, wtf2);
    k_cvt4<<<(NNODES * 128 / 4 + 255) / 256, 256, 0, stream>>>(x, x16, NNODES * 128 / 4);

    // layer 1 (fused aggregate + GEMM + relu)
    k_l1_fused<<<MB, 256, 0, stream>>>(x16, rowofs, edges, dinv, wt1, b1, bufB);
    // layer 2
    k_aggregate<2><<<AGG, 256, 0, stream>>>(bufB, rowofs, edges, dinv, bufA);
    k_gemm_mfma<0, 0><<<dim3(2, MB), 256, 0, stream>>>(bufA, wt2, b2, bufB, batch, nullptr, NNODES, 256, 128);
    // layer 3 + fused pool
    k_aggregate<4><<<AGG, 256, 0, stream>>>(bufB, rowofs, edges, dinv, bufA);
    k_gemm_mfma<2, 0><<<dim3(4, MB), 256, 0, stream>>>(bufA, wt3, b3, nullptr, batch, gp, NNODES, 512, 256);

    // MLP head via MFMA (FC1 reads gp fp32 directly)
    k_gemm_mfma<0, 1><<<dim3(8, NGRAPH / 64), 256, 0, stream>>>(gp, wtf1, bf1, f1, batch, nullptr, NGRAPH, 1024, 512);
    k_gemm_mfma<1, 0><<<dim3(1, NGRAPH / 64), 256, 0, stream>>>(f1, wtf2, bf2, out, batch, nullptr, NGRAPH, 128, 1024);
}

// Round 8
// 417.903 us; speedup vs baseline: 1.1695x; 1.1695x over previous
//
#include <hip/hip_runtime.h>

#define NNODES 50000
#define NEDGES 800000
#define NGRAPH 512

typedef short bf16x8 __attribute__((ext_vector_type(8)));
typedef unsigned short u16x8 __attribute__((ext_vector_type(8)));
typedef float f32x4 __attribute__((ext_vector_type(4)));

// ---------- bf16 <-> fp32 helpers ----------
static __device__ __forceinline__ float b2f(unsigned short u) {
    return __uint_as_float(((unsigned)u) << 16);
}
static __device__ __forceinline__ unsigned short f2b(float f) {
    unsigned u = __float_as_uint(f);
    unsigned r = (u + 0x7fffu + ((u >> 16) & 1u)) >> 16;  // round-nearest-even
    return (unsigned short)r;
}

// row-fragment loads (bf16 rows)
static __device__ __forceinline__ void ldrow(const unsigned short* X, size_t off, float (&v)[2]) {
    unsigned u = *(const unsigned*)(X + off);
    v[0] = b2f((unsigned short)(u & 0xffff));
    v[1] = b2f((unsigned short)(u >> 16));
}
static __device__ __forceinline__ void ldrow(const unsigned short* X, size_t off, float (&v)[4]) {
    uint2 u = *(const uint2*)(X + off);
    v[0] = b2f((unsigned short)(u.x & 0xffff));
    v[1] = b2f((unsigned short)(u.x >> 16));
    v[2] = b2f((unsigned short)(u.y & 0xffff));
    v[3] = b2f((unsigned short)(u.y >> 16));
}

// ---------- setup: deg_cnt init + gp zero ----------
__global__ void k_setup(unsigned long long* deg_cnt, int* gp) {
    int i = blockIdx.x * 256 + threadIdx.x;
    if (i < NNODES) deg_cnt[i] = (unsigned long long)(1u << 24);  // self-loop w=1 (8.24 fixed)
    if (i < NGRAPH * 512) gp[i] = 0;                              // +0.0f bits
}

// packed u64 atomic: hi32 = count, lo32 = 8.24 fixed-point weighted degree
__global__ void k_count(const int* __restrict__ ei, const float* __restrict__ ew,
                        unsigned long long* deg_cnt) {
    int e = blockIdx.x * 256 + threadIdx.x;
    if (e < NEDGES) {
        int d = ei[NEDGES + e];
        unsigned fixed = __float2uint_rn(ew[e] * 16777216.0f);  // 2^24; ew in [0,1)
        atomicAdd(&deg_cnt[d], ((unsigned long long)1 << 32) | fixed);
    }
}

// ---------- 3-phase exclusive scan (+dinv unpack fused into phase 1) ----------
__global__ void k_scan1(const unsigned long long* __restrict__ deg_cnt,
                        float* __restrict__ dinv,
                        int* __restrict__ ofs, int* __restrict__ bsum, int n) {
    __shared__ int wsum[4];
    const int tid = threadIdx.x, lane = tid & 63, wid = tid >> 6;
    const int idx = blockIdx.x * 256 + tid;
    int v = 0;
    if (idx < n) {
        unsigned long long dc = deg_cnt[idx];
        v = (int)(dc >> 32);
        dinv[idx] = rsqrtf((float)(unsigned)(dc & 0xffffffffull) * 5.9604645e-8f);  // *2^-24
    }
    int s = v;
    #pragma unroll
    for (int off = 1; off < 64; off <<= 1) {
        int y = __shfl_up(s, off, 64);
        if (lane >= off) s += y;
    }
    if (lane == 63) wsum[wid] = s;
    __syncthreads();
    int waveoff = 0;
    for (int w = 0; w < wid; ++w) waveoff += wsum[w];
    if (idx < n) ofs[idx] = waveoff + s - v;
    if (tid == 255) bsum[blockIdx.x] = waveoff + s;
}
__global__ void k_scan2(int* __restrict__ bsum, int nb) {
    __shared__ int wsum[4];
    const int tid = threadIdx.x, lane = tid & 63, wid = tid >> 6;
    int v = (tid < nb) ? bsum[tid] : 0;
    int s = v;
    #pragma unroll
    for (int off = 1; off < 64; off <<= 1) {
        int y = __shfl_up(s, off, 64);
        if (lane >= off) s += y;
    }
    if (lane == 63) wsum[wid] = s;
    __syncthreads();
    int waveoff = 0;
    for (int w = 0; w < wid; ++w) waveoff += wsum[w];
    if (tid < nb) bsum[tid] = waveoff + s - v;
    if (tid == 255) bsum[nb] = waveoff + s;
}
// final offsets into BOTH rowofs (read-only CSR) and cursor (atomic fill state)
__global__ void k_scan3(int* __restrict__ ofs, int* __restrict__ cursor,
                        const int* __restrict__ bsum, int n) {
    const int idx = blockIdx.x * 256 + threadIdx.x;
    if (idx < n) {
        int v = ofs[idx] + bsum[blockIdx.x];
        ofs[idx] = v;
        cursor[idx] = v;
    }
    if (idx == 0) ofs[n] = bsum[gridDim.x];
}

// per edge: one atomic + one packed 8B store. coef = ew*dinv[src] (dinv[dst] hoisted to aggregate)
__global__ void k_fill(const int* __restrict__ ei, const float* __restrict__ ew,
                       const float* __restrict__ dinv, int* cursor,
                       unsigned long long* __restrict__ edges) {
    int e = blockIdx.x * 256 + threadIdx.x;
    if (e < NEDGES) {
        int s = ei[e];
        int d = ei[NEDGES + e];
        float c = ew[e] * dinv[s];
        int pos = atomicAdd(&cursor[d], 1);
        edges[pos] = ((unsigned long long)__float_as_uint(c) << 32) | (unsigned)s;
    }
}

// ---------- all 5 weight transposes in one kernel: W[K][N] fp32 -> WT[N][K] bf16 ----------
__global__ void k_wt_all(const float* __restrict__ W1, const float* __restrict__ W2,
                         const float* __restrict__ W3, const float* __restrict__ Wf1,
                         const float* __restrict__ Wf2,
                         unsigned short* __restrict__ T1, unsigned short* __restrict__ T2,
                         unsigned short* __restrict__ T3, unsigned short* __restrict__ Tf1,
                         unsigned short* __restrict__ Tf2) {
    int i = blockIdx.x * 256 + threadIdx.x;
    const float* W; unsigned short* T; int K, ns;
    if (i < 16384)        { W = W1;  T = T1;  K = 128;  ns = 7;  }
    else if (i < 49152)   { W = W2;  T = T2;  K = 128;  ns = 8;  i -= 16384; }
    else if (i < 180224)  { W = W3;  T = T3;  K = 256;  ns = 9;  i -= 49152; }
    else if (i < 704512)  { W = Wf1; T = Tf1; K = 512;  ns = 10; i -= 180224; }
    else if (i < 835584)  { W = Wf2; T = Tf2; K = 1024; ns = 7;  i -= 704512; }
    else return;
    int k = i >> ns, n = i & ((1 << ns) - 1);
    T[(size_t)n * K + k] = f2b(W[i]);
}

// fp32 -> bf16 elementwise (n4 = n/4)
__global__ void k_cvt4(const float* __restrict__ X, unsigned short* __restrict__ Y, int n4) {
    int i = blockIdx.x * 256 + threadIdx.x;
    if (i < n4) {
        float4 v = ((const float4*)X)[i];
        uint2 o;
        o.x = (unsigned)f2b(v.x) | ((unsigned)f2b(v.y) << 16);
        o.y = (unsigned)f2b(v.z) | ((unsigned)f2b(v.w) << 16);
        ((uint2*)Y)[i] = o;
    }
}

// ---------- aggregation: Z[i,:] = dinv[i] * (dinv[i]*X[i,:] + sum_e coef_e * X[col_e,:]) ----------
// wave-per-node, lane owns VEC elems (F = 64*VEC), packed (coef,col) edges, unroll x8 + x4 + tail.
template <int VEC>
__global__ __launch_bounds__(256) void k_aggregate(const unsigned short* __restrict__ X,
                                                   const int* __restrict__ row_ofs,
                                                   const unsigned long long* __restrict__ edges,
                                                   const float* __restrict__ dinv,
                                                   unsigned short* __restrict__ Z) {
    const int F = 64 * VEC;
    const int wave = threadIdx.x >> 6, lane = threadIdx.x & 63;
    const int node = blockIdx.x * 4 + wave;
    if (node >= NNODES) return;
    const int fo = lane * VEC;
    const float di = dinv[node];

    float acc[VEC], v[VEC];
    ldrow(X, (size_t)node * F + fo, v);
    #pragma unroll
    for (int j = 0; j < VEC; ++j) acc[j] = di * v[j];

    int e = row_ofs[node];
    const int end = row_ofs[node + 1];
    // 8-deep: 8 independent row-gathers in flight per wave
    for (; e + 8 <= end; e += 8) {
        unsigned long long pk[8];
        float vv[8][VEC];
        #pragma unroll
        for (int u = 0; u < 8; ++u) pk[u] = edges[e + u];
        #pragma unroll
        for (int u = 0; u < 8; ++u) ldrow(X, (size_t)(unsigned)pk[u] * F + fo, vv[u]);
        #pragma unroll
        for (int u = 0; u < 8; ++u) {
            float c = __uint_as_float((unsigned)(pk[u] >> 32));
            #pragma unroll
            for (int j = 0; j < VEC; ++j) acc[j] += c * vv[u][j];
        }
    }
    for (; e + 4 <= end; e += 4) {
        unsigned long long pk[4];
        float vv[4][VEC];
        #pragma unroll
        for (int u = 0; u < 4; ++u) pk[u] = edges[e + u];
        #pragma unroll
        for (int u = 0; u < 4; ++u) ldrow(X, (size_t)(unsigned)pk[u] * F + fo, vv[u]);
        #pragma unroll
        for (int u = 0; u < 4; ++u) {
            float c = __uint_as_float((unsigned)(pk[u] >> 32));
            #pragma unroll
            for (int j = 0; j < VEC; ++j) acc[j] += c * vv[u][j];
        }
    }
    for (; e < end; ++e) {
        unsigned long long pe = edges[e];
        float c = __uint_as_float((unsigned)(pe >> 32));
        ldrow(X, (size_t)(unsigned)pe * F + fo, v);
        #pragma unroll
        for (int j = 0; j < VEC; ++j) acc[j] += c * v[j];
    }

    if constexpr (VEC == 2) {
        unsigned o = (unsigned)f2b(di * acc[0]) | ((unsigned)f2b(di * acc[1]) << 16);
        *(unsigned*)(Z + (size_t)node * F + fo) = o;
    } else {
        uint2 o;
        o.x = (unsigned)f2b(di * acc[0]) | ((unsigned)f2b(di * acc[1]) << 16);
        o.y = (unsigned)f2b(di * acc[2]) | ((unsigned)f2b(di * acc[3]) << 16);
        *(uint2*)(Z + (size_t)node * F + fo) = o;
    }
}

// ---------- bf16 MFMA GEMM: C = epi(A[MxK] @ WT[NxK]^T + bias) ----------
// block 64(M) x 128(N), 4 waves (2x2 of 32x64), BK=32, 16x16x32 MFMA.
// CMODE 0: bf16 store + relu. 1: fp32 store, no relu. 2: fused per-graph relu+max-pool into gp.
// AFP: A is fp32 (converted to bf16 during staging).
template <int CMODE, int AFP>
__global__ __launch_bounds__(256) void k_gemm_mfma(const void* __restrict__ Av,
                                                   const unsigned short* __restrict__ WT,
                                                   const float* __restrict__ bias,
                                                   void* __restrict__ Cv,
                                                   const int* __restrict__ batch,
                                                   int* __restrict__ gp,
                                                   int M, int N, int K) {
    constexpr int LDK = 40;
    __shared__ unsigned short As[64 * LDK];
    __shared__ unsigned short Bs[128 * LDK];
    const int tid = threadIdx.x;
    const int m0 = blockIdx.y * 64, n0 = blockIdx.x * 128;
    const int wave = tid >> 6, lane = tid & 63;
    const int wm = (wave >> 1) * 32;
    const int wn = (wave & 1) * 64;
    const int quad = lane >> 4, mrow = lane & 15;

    const int ar = tid >> 2;
    const int ak = (tid & 3) * 8;
    const bool arow_ok = (m0 + ar) < M;
    const size_t aoff = (size_t)(m0 + ar) * K + ak;
    const unsigned short* Bg0 = WT + (size_t)(n0 + ar) * K + ak;
    const unsigned short* Bg1 = WT + (size_t)(n0 + ar + 64) * K + ak;

    f32x4 acc[2][4] = {};

    for (int k0 = 0; k0 < K; k0 += 32) {
        u16x8 av = {};
        if (arow_ok) {
            if constexpr (AFP) {
                const float* Af = (const float*)Av + aoff + k0;
                float4 f0 = *(const float4*)Af;
                float4 f1 = *(const float4*)(Af + 4);
                av[0] = (short)f2b(f0.x); av[1] = (short)f2b(f0.y);
                av[2] = (short)f2b(f0.z); av[3] = (short)f2b(f0.w);
                av[4] = (short)f2b(f1.x); av[5] = (short)f2b(f1.y);
                av[6] = (short)f2b(f1.z); av[7] = (short)f2b(f1.w);
            } else {
                av = *(const u16x8*)((const unsigned short*)Av + aoff + k0);
            }
        }
        u16x8 bv0 = *(const u16x8*)(Bg0 + k0);
        u16x8 bv1 = *(const u16x8*)(Bg1 + k0);
        *(u16x8*)&As[ar * LDK + ak] = av;
        *(u16x8*)&Bs[ar * LDK + ak] = bv0;
        *(u16x8*)&Bs[(ar + 64) * LDK + ak] = bv1;
        __syncthreads();
        bf16x8 af[2], bf[4];
        #pragma unroll
        for (int mt = 0; mt < 2; ++mt)
            af[mt] = *(const bf16x8*)&As[(wm + mt * 16 + mrow) * LDK + quad * 8];
        #pragma unroll
        for (int nt = 0; nt < 4; ++nt)
            bf[nt] = *(const bf16x8*)&Bs[(wn + nt * 16 + mrow) * LDK + quad * 8];
        #pragma unroll
        for (int mt = 0; mt < 2; ++mt)
            #pragma unroll
            for (int nt = 0; nt < 4; ++nt)
                acc[mt][nt] = __builtin_amdgcn_mfma_f32_16x16x32_bf16(af[mt], bf[nt], acc[mt][nt], 0, 0, 0);
        __syncthreads();
    }

    float bn[4];
    #pragma unroll
    for (int nt = 0; nt < 4; ++nt) bn[nt] = bias[n0 + wn + nt * 16 + mrow];

    if constexpr (CMODE == 0) {
        unsigned short* C = (unsigned short*)Cv;
        #pragma unroll
        for (int mt = 0; mt < 2; ++mt) {
            #pragma unroll
            for (int r = 0; r < 4; ++r) {
                int row = m0 + wm + mt * 16 + quad * 4 + r;
                if (row < M) {
                    #pragma unroll
                    for (int nt = 0; nt < 4; ++nt) {
                        float v = fmaxf(acc[mt][nt][r] + bn[nt], 0.f);
                        C[(size_t)row * N + n0 + wn + nt * 16 + mrow] = f2b(v);
                    }
                }
            }
        }
    } else if constexpr (CMODE == 1) {
        float* C = (float*)Cv;
        #pragma unroll
        for (int mt = 0; mt < 2; ++mt) {
            #pragma unroll
            for (int r = 0; r < 4; ++r) {
                int row = m0 + wm + mt * 16 + quad * 4 + r;
                if (row < M) {
                    #pragma unroll
                    for (int nt = 0; nt < 4; ++nt)
                        C[(size_t)row * N + n0 + wn + nt * 16 + mrow] = acc[mt][nt][r] + bn[nt];
                }
            }
        }
    } else {
        // fused pool: block's 64 rows span <=2 graphs (min graph size 97)
        __shared__ float pools[2][2][128];
        const int g0 = batch[m0];
        int last = m0 + 63; if (last >= M) last = M - 1;
        const int gl = batch[last];
        int  gid[8];
        bool rok[8];
        #pragma unroll
        for (int mt = 0; mt < 2; ++mt)
            #pragma unroll
            for (int r = 0; r < 4; ++r) {
                int row = m0 + wm + mt * 16 + quad * 4 + r;
                rok[mt * 4 + r] = row < M;
                gid[mt * 4 + r] = (row < M) ? batch[row] : -1;
            }
        #pragma unroll
        for (int nt = 0; nt < 4; ++nt) {
            float v0 = 0.f, v1 = 0.f;
            #pragma unroll
            for (int mt = 0; mt < 2; ++mt)
                #pragma unroll
                for (int r = 0; r < 4; ++r) {
                    if (rok[mt * 4 + r]) {
                        float v = fmaxf(acc[mt][nt][r] + bn[nt], 0.f);
                        if (gid[mt * 4 + r] == g0) v0 = fmaxf(v0, v);
                        else v1 = fmaxf(v1, v);
                    }
                }
            v0 = fmaxf(v0, __shfl_xor(v0, 16, 64));
            v0 = fmaxf(v0, __shfl_xor(v0, 32, 64));
            v1 = fmaxf(v1, __shfl_xor(v1, 16, 64));
            v1 = fmaxf(v1, __shfl_xor(v1, 32, 64));
            if (quad == 0) {
                int c = wn + nt * 16 + mrow;
                pools[wm >> 5][0][c] = v0;
                pools[wm >> 5][1][c] = v1;
            }
        }
        __syncthreads();
        int c = tid & 127, gi = tid >> 7;
        float v = fmaxf(pools[0][gi][c], pools[1][gi][c]);
        int g = gi ? gl : g0;
        if (gi == 0 || gl != g0)
            atomicMax(&gp[(size_t)g * N + n0 + c], __float_as_int(v));
    }
}

extern "C" void kernel_launch(void* const* d_in, const int* in_sizes, int n_in,
                              void* d_out, int out_size, void* d_ws, size_t ws_size,
                              hipStream_t stream) {
    const float* x   = (const float*)d_in[0];
    const float* ew  = (const float*)d_in[1];
    const float* W1  = (const float*)d_in[2];
    const float* b1  = (const float*)d_in[3];
    const float* W2  = (const float*)d_in[4];
    const float* b2  = (const float*)d_in[5];
    const float* W3  = (const float*)d_in[6];
    const float* b3  = (const float*)d_in[7];
    const float* Wf1 = (const float*)d_in[8];
    const float* bf1 = (const float*)d_in[9];
    const float* Wf2 = (const float*)d_in[10];
    const float* bf2 = (const float*)d_in[11];
    const int* ei    = (const int*)d_in[12];
    const int* batch = (const int*)d_in[13];
    float* out = (float*)d_out;
    (void)in_sizes; (void)n_in; (void)out_size; (void)ws_size;

    char* p = (char*)d_ws;
    auto alloc = [&](size_t bytes) -> char* {
        char* r = p;
        p += (bytes + 255) & ~(size_t)255;
        return r;
    };
    const int nbN = (NNODES + 255) / 256;   // 196
    unsigned long long* deg_cnt = (unsigned long long*)alloc((size_t)NNODES * 8);
    float* dinv   = (float*)alloc((size_t)NNODES * 4);
    int*   cursor = (int*)  alloc((size_t)NNODES * 4);
    int*   rowofs = (int*)  alloc((size_t)(NNODES + 1) * 4);
    int*   bsum   = (int*)  alloc((size_t)(nbN + 1) * 4);
    unsigned long long* edges = (unsigned long long*)alloc((size_t)NEDGES * 8);  // packed (coef,col)
    int*   gp     = (int*)  alloc((size_t)NGRAPH * 512 * 4);
    unsigned short* f1   = (unsigned short*)alloc((size_t)NGRAPH * 1024 * 2);
    unsigned short* wt1  = (unsigned short*)alloc((size_t)128 * 128 * 2);
    unsigned short* wt2  = (unsigned short*)alloc((size_t)256 * 128 * 2);
    unsigned short* wt3  = (unsigned short*)alloc((size_t)512 * 256 * 2);
    unsigned short* wtf1 = (unsigned short*)alloc((size_t)1024 * 512 * 2);
    unsigned short* wtf2 = (unsigned short*)alloc((size_t)128 * 1024 * 2);
    unsigned short* bufA = (unsigned short*)alloc((size_t)NNODES * 256 * 2);
    unsigned short* bufB = (unsigned short*)alloc((size_t)NNODES * 256 * 2);
    unsigned short* x16  = bufB;  // alias: x16 consumed by agg-1 before gemm-1 overwrites bufB
    // total ~63 MB

    const int nbE = (NEDGES + 255) / 256;
    const int MB = (NNODES + 63) / 64;      // 782
    const int AGG = (NNODES + 3) / 4;

    // graph preprocessing (shared by all 3 conv layers)
    k_setup<<<1024, 256, 0, stream>>>(deg_cnt, gp);
    k_count<<<nbE, 256, 0, stream>>>(ei, ew, deg_cnt);
    k_scan1<<<nbN, 256, 0, stream>>>(deg_cnt, dinv, rowofs, bsum, NNODES);
    k_scan2<<<1, 256, 0, stream>>>(bsum, nbN);
    k_scan3<<<nbN, 256, 0, stream>>>(rowofs, cursor, bsum, NNODES);
    k_fill<<<nbE, 256, 0, stream>>>(ei, ew, dinv, cursor, edges);
    k_wt_all<<<(835584 + 255) / 256, 256, 0, stream>>>(W1, W2, W3, Wf1, Wf2,
                                                       wt1, wt2, wt3, wtf1, wtf2);
    k_cvt4<<<(NNODES * 128 / 4 + 255) / 256, 256, 0, stream>>>(x, x16, NNODES * 128 / 4);

    // layer 1
    k_aggregate<2><<<AGG, 256, 0, stream>>>(x16, rowofs, edges, dinv, bufA);
    k_gemm_mfma<0, 0><<<dim3(1, MB), 256, 0, stream>>>(bufA, wt1, b1, bufB, batch, nullptr, NNODES, 128, 128);
    // layer 2
    k_aggregate<2><<<AGG, 256, 0, stream>>>(bufB, rowofs, edges, dinv, bufA);
    k_gemm_mfma<0, 0><<<dim3(2, MB), 256, 0, stream>>>(bufA, wt2, b2, bufB, batch, nullptr, NNODES, 256, 128);
    // layer 3 + fused pool
    k_aggregate<4><<<AGG, 256, 0, stream>>>(bufB, rowofs, edges, dinv, bufA);
    k_gemm_mfma<2, 0><<<dim3(4, MB), 256, 0, stream>>>(bufA, wt3, b3, nullptr, batch, gp, NNODES, 512, 256);

    // MLP head via MFMA (FC1 reads gp fp32 directly)
    k_gemm_mfma<0, 1><<<dim3(8, NGRAPH / 64), 256, 0, stream>>>(gp, wtf1, bf1, f1, batch, nullptr, NGRAPH, 1024, 512);
    k_gemm_mfma<1, 0><<<dim3(1, NGRAPH / 64), 256, 0, stream>>>(f1, wtf2, bf2, out, batch, nullptr, NGRAPH, 128, 1024);
}